// Round 1
// baseline (189.015 us; speedup 1.0000x reference)
//
#include <hip/hip_runtime.h>

// OpeningLoss2D: grey_opening(x, size=2) per 2D map, then mean((x - open)^2).
// size=2 -> erosion offsets [-1,0], dilation offsets [0,+1], symmetric pad ==
// edge clamp for pad width 1. Fully separable; streamed through registers.

constexpr int W = 512;
constexpr int H = 512;
constexpr int RPW = 16;                  // rows per wave strip
constexpr int STRIPS_PER_IMG = H / RPW;  // 32

__device__ __forceinline__ void load_row8(const float* p, float v[8]) {
  float4 a = *reinterpret_cast<const float4*>(p);
  float4 b = *reinterpret_cast<const float4*>(p + 4);
  v[0] = a.x; v[1] = a.y; v[2] = a.z; v[3] = a.w;
  v[4] = b.x; v[5] = b.y; v[6] = b.z; v[7] = b.w;
}

// cm[c] = min(x[c-1], x[c]), col -1 clamps to col 0
__device__ __forceinline__ void colmin8(const float v[8], float cm[8], int lane) {
  float left = __shfl_up(v[7], 1);  // lane-1's last element
  if (lane == 0) left = v[0];       // clamp at global col 0
  cm[0] = fminf(left, v[0]);
#pragma unroll
  for (int k = 1; k < 8; ++k) cm[k] = fminf(v[k - 1], v[k]);
}

// dm[c] = max(e[c], e[c+1]), col W clamps to col W-1
__device__ __forceinline__ void colmax8(const float e[8], float dm[8], int lane) {
  float right = __shfl_down(e[0], 1);  // lane+1's first element
  if (lane == 63) right = e[7];        // clamp at global col W-1
#pragma unroll
  for (int k = 0; k < 7; ++k) dm[k] = fmaxf(e[k], e[k + 1]);
  dm[7] = fmaxf(e[7], right);
}

__global__ __launch_bounds__(256) void open_loss_partial(
    const float* __restrict__ x, float* __restrict__ partial, int nWaves) {
  const int tid = blockIdx.x * blockDim.x + threadIdx.x;
  const int wave = tid >> 6;
  const int lane = threadIdx.x & 63;

  float acc = 0.f;
  if (wave < nWaves) {  // wave-uniform branch
    const int img = wave / STRIPS_PER_IMG;
    const int strip = wave % STRIPS_PER_IMG;
    const float* base = x + (size_t)img * (H * W) + lane * 8;
    const int rs = strip * RPW;
    const int re = rs + RPW - 1;

    float xp[8], cmp[8], dmp[8];
    float v[8], cm[8], er[8];

    // cm of row rs-1 (clamped to 0: symmetric pad == edge row)
    load_row8(base + (size_t)(rs > 0 ? rs - 1 : 0) * W, v);
    colmin8(v, cmp, lane);

    // row rs: er = min(cm_{rs-1}, cm_rs); dm_rs
    load_row8(base + (size_t)rs * W, v);
    colmin8(v, cm, lane);
#pragma unroll
    for (int k = 0; k < 8; ++k) er[k] = fminf(cmp[k], cm[k]);
    colmax8(er, dmp, lane);
#pragma unroll
    for (int k = 0; k < 8; ++k) { xp[k] = v[k]; cmp[k] = cm[k]; }

    for (int i = rs; i <= re; ++i) {
      if (i < H - 1) {  // wave-uniform
        load_row8(base + (size_t)(i + 1) * W, v);
        colmin8(v, cm, lane);
        float dmn[8];
#pragma unroll
        for (int k = 0; k < 8; ++k) er[k] = fminf(cmp[k], cm[k]);
        colmax8(er, dmn, lane);
#pragma unroll
        for (int k = 0; k < 8; ++k) {
          float di = fmaxf(dmp[k], dmn[k]);  // max(dm_i, dm_{i+1})
          float d = xp[k] - di;
          acc = fmaf(d, d, acc);
          xp[k] = v[k]; cmp[k] = cm[k]; dmp[k] = dmn[k];
        }
      } else {  // i == H-1: dm_{i+1} clamps to dm_i
#pragma unroll
        for (int k = 0; k < 8; ++k) {
          float d = xp[k] - dmp[k];
          acc = fmaf(d, d, acc);
        }
      }
    }
  }

  // wave reduce (64 lanes), then block reduce, one partial per block
#pragma unroll
  for (int off = 32; off > 0; off >>= 1) acc += __shfl_down(acc, off);
  __shared__ float sh[4];
  const int wid = threadIdx.x >> 6;
  if (lane == 0) sh[wid] = acc;
  __syncthreads();
  if (threadIdx.x == 0) partial[blockIdx.x] = sh[0] + sh[1] + sh[2] + sh[3];
}

__global__ __launch_bounds__(256) void reduce_final(
    const float* __restrict__ partial, int n, float* __restrict__ out,
    double invN) {
  double s = 0.0;
  for (int i = threadIdx.x; i < n; i += blockDim.x) s += (double)partial[i];
#pragma unroll
  for (int off = 32; off > 0; off >>= 1) s += __shfl_down(s, off);
  __shared__ double sh[4];
  const int wid = threadIdx.x >> 6;
  if ((threadIdx.x & 63) == 0) sh[wid] = s;
  __syncthreads();
  if (threadIdx.x == 0) {
    double tot = sh[0] + sh[1] + sh[2] + sh[3];
    out[0] = (float)(tot * invN);
  }
}

extern "C" void kernel_launch(void* const* d_in, const int* in_sizes, int n_in,
                              void* d_out, int out_size, void* d_ws, size_t ws_size,
                              hipStream_t stream) {
  const float* x = (const float*)d_in[0];
  float* out = (float*)d_out;
  float* partial = (float*)d_ws;

  const long long n = in_sizes[0];               // 16*8*512*512 = 33554432
  const int nImg = (int)(n / ((long long)H * W));  // 128
  const int nWaves = nImg * STRIPS_PER_IMG;        // 4096
  const int nBlocks = nWaves / 4;                  // 1024 blocks of 4 waves

  open_loss_partial<<<nBlocks, 256, 0, stream>>>(x, partial, nWaves);
  reduce_final<<<1, 256, 0, stream>>>(partial, nBlocks, out,
                                      1.0 / (double)n);
}